// Round 11
// baseline (255.956 us; speedup 1.0000x reference)
//
#include <hip/hip_runtime.h>
#include <stdint.h>

typedef _Float16 h2 __attribute__((ext_vector_type(2)));

static constexpr int CDIM = 32;     // channels
static constexpr int NPIX = 16384;  // H*W = 128*128
static constexpr int SSAM = 1024;   // samples per row
static constexpr int TILE = 8;      // 8x8 pixel tile per block
static constexpr int HALO = 12;     // (25-1)/2 local window halo
static constexpr int WIN  = 32;     // TILE + 2*HALO = 32 window grid

__device__ __forceinline__ uint16_t f2h(float f) {
    union { _Float16 h; uint16_t u; } c;
    c.h = (_Float16)f;
    return c.u;
}

// cross-lane add via DPP quad_perm (VALU-only).
template<int CTRL>
__device__ __forceinline__ float dpp_add(float x) {
    int y = __builtin_amdgcn_mov_dpp(__float_as_int(x), CTRL, 0xF, 0xF, true);
    return x + __int_as_float(y);
}

// broadcast quad-lane Q's value to all 4 lanes of the quad.
template<int Q>
__device__ __forceinline__ int qbcast(int x) {
    return __builtin_amdgcn_mov_dpp(x, Q * 0x55, 0xF, 0xF, true);
}

__device__ __forceinline__ float dot2(h2 a, h2 b, float c) {
    return __builtin_amdgcn_fdot2(a, b, c, false);   // v_dot2_f32_f16
}

// ---------------------------------------------------------------------------
// Kernel 0: zero the segbit workspace.
// ---------------------------------------------------------------------------
__global__ __launch_bounds__(256)
void zero_words(uint32_t* __restrict__ p, int nwords)
{
    int i = blockIdx.x * 256 + threadIdx.x;
    if (i < nwords) p[i] = 0;
}

// ---------------------------------------------------------------------------
// Kernel 1: layout prep. key/query [B][C][N] f32 -> [B*N][32] f16 rows
// (64B, line-aligned); query pre-scaled by C^-0.5.
// ---------------------------------------------------------------------------
__global__ __launch_bounds__(256)
void prep_kernel(const float* __restrict__ key_f,
                 const float* __restrict__ query_f,
                 uint8_t* __restrict__ key16,
                 uint8_t* __restrict__ q16,
                 int N, int rows, float scale)
{
    int gI = blockIdx.x * 256 + threadIdx.x;
    if (gI >= rows) return;
    int b = gI / N, n = gI - b * N;
    const size_t cb = (size_t)b * CDIM;

    uint32_t kp[16], qp[16];
#pragma unroll
    for (int c = 0; c < CDIM; c += 2) {
        float k0 = key_f[(cb + c) * N + n];
        float k1 = key_f[(cb + c + 1) * N + n];
        float q0 = query_f[(cb + c) * N + n] * scale;
        float q1 = query_f[(cb + c + 1) * N + n] * scale;
        kp[c >> 1] = (uint32_t)f2h(k0) | ((uint32_t)f2h(k1) << 16);
        qp[c >> 1] = (uint32_t)f2h(q0) | ((uint32_t)f2h(q1) << 16);
    }
    uint4* ko = (uint4*)(key16 + ((size_t)gI << 6));
    uint4* qo = (uint4*)(q16 + ((size_t)gI << 6));
#pragma unroll
    for (int j = 0; j < 4; ++j) {
        ko[j] = make_uint4(kp[4*j], kp[4*j+1], kp[4*j+2], kp[4*j+3]);
        qo[j] = make_uint4(qp[4*j], qp[4*j+1], qp[4*j+2], qp[4*j+3]);
    }
}

// ---------------------------------------------------------------------------
// Kernel 1b: segment bitmap. segbit[b][v][512]: bit n set iff seg[b][n]==v.
// ---------------------------------------------------------------------------
__global__ __launch_bounds__(256)
void segbit_build(const int* __restrict__ seg32,
                  uint32_t* __restrict__ segbit,
                  int N, int rows)
{
    int g = blockIdx.x * 256 + threadIdx.x;
    if (g >= rows) return;
    int b = g / N, n = g - b * N;
    int v = seg32[g] & 63;
    atomicOr(&segbit[(((size_t)(b * 64 + v)) << 9) + (n >> 5)], 1u << (n & 31));
}

// ---------------------------------------------------------------------------
// Kernel 2 (fast): spatial-tile blocks. Each block = 8x8 pixels (64 rows).
// The 32x32 clamped key window (64KB) is staged in LDS ONCE; any sample whose
// (r,c) falls inside the window is served from LDS (all 625 local-window
// samples by construction + ~6% of randoms) -> ~62% fewer L2 gather lines,
// attacking the measured 0.3 lines/cyc/CU MSHR wall.
// Correct for ARBITRARY sample_inds (pure geometric cache test).
// Sample indices live in registers (own int4 + DPP quad-broadcast): no idx
// LDS, logit store = one coalesced float4/lane. One barrier per row.
// Fixed geometry: N=16384 (W=H=128), S=1024, C=32.
// ---------------------------------------------------------------------------
__global__ __launch_bounds__(256)
void affinity_tile(const int* __restrict__ inds,
                   const uint8_t* __restrict__ key16,
                   const uint8_t* __restrict__ q16,
                   const int* __restrict__ seg32,
                   const uint32_t* __restrict__ segbit,
                   float* __restrict__ out,
                   float* __restrict__ ws_kl)
{
    const int tid  = threadIdx.x;
    const int bid  = blockIdx.x;
    const int b    = bid >> 8;             // 256 tiles per batch image
    const int t    = bid & 255;
    const int y0   = (t >> 4) << 3;
    const int x0   = (t & 15) << 3;
    const int lane = tid & 63;
    const int w    = tid >> 6;
    const int sub  = lane & 3;

    const int yL = max(0, y0 - HALO);
    const int yH = min(127, y0 + TILE - 1 + HALO);
    const int xL = max(0, x0 - HALO);
    const int xH = min(127, x0 + TILE - 1 + HALO);
    const int wh = yH - yL + 1;            // <= 32
    const int ww = xH - xL + 1;            // <= 32

    __shared__ __align__(16) uint8_t  key_lds[WIN * WIN * 64];  // 64KB
    __shared__ __align__(16) uint32_t bm_lds[2][512];           // 2 x 2KB
    __shared__ float red[2][3][4];                              // [par][Z,T,SL][wave]

    const uint8_t* kb = key16 + ((size_t)b << 20);   // b * N * 64 (uniform)
    const uint32_t subs = (uint32_t)(sub << 4);

    // ---- stage key window: slot (i,j) <- key row (yL+min(i,wh-1))*128 + ... ----
    for (int s = tid; s < WIN * WIN * 4; s += 256) {
        int slot = s >> 2, q = s & 3;
        int i = slot >> 5, j = slot & 31;
        int ii = min(i, wh - 1), jj = min(j, ww - 1);
        *(uint4*)(key_lds + (slot << 6) + (q << 4)) =
            *(const uint4*)(kb + ((((yL + ii) << 7) + (xL + jj)) << 6) + (q << 4));
    }

    // ---- row 0 state: seg, bitmap slice, query fragment, indices ----
    const uint32_t* sbm = segbit + ((size_t)(b * 64) << 9);
    int row = (b << 14) + (y0 << 7) + x0;            // r = 0
    int scur = seg32[row];
    ((uint2*)bm_lds[0])[tid] = ((const uint2*)(sbm + ((size_t)(scur & 63) << 9)))[tid];
    uint4 qcur = *(const uint4*)(q16 + ((size_t)row << 6) + subs);
    int4  ivcur = ((const int4*)(inds + ((size_t)row << 10)))[tid];
    __syncthreads();   // key_lds + bm_lds visibility

    for (int r = 0; r < TILE * TILE; ++r) {
        const int p = r & 1;
        const bool hasNext = (r + 1 < TILE * TILE);
        const int rn = r + 1;
        const int rown = (b << 14) + ((y0 + (rn >> 3)) << 7) + (x0 + (rn & 7));

        h2 qh0, qh1, qh2, qh3;
        {
            union { uint4 u; h2 h[4]; } qc; qc.u = qcur;
            qh0 = qc.h[0]; qh1 = qc.h[1]; qh2 = qc.h[2]; qh3 = qc.h[3];
        }
        const int seg_n = scur;
        const int4 iv = ivcur;

        // ---- pass 1: classify all 16 group-samples; issue miss gathers ----
        uint4 kd[16];
#define CLS(I) { \
        int comp = (((I)&3)==0) ? iv.x : (((I)&3)==1) ? iv.y : (((I)&3)==2) ? iv.z : iv.w; \
        int idx  = qbcast<((I)>>2)>(comp); \
        int rr = (idx >> 7) - yL, cc = (idx & 127) - xL; \
        if (!((uint32_t)rr < (uint32_t)wh && (uint32_t)cc < (uint32_t)ww)) \
            kd[(I)] = *(const uint4*)(kb + (((uint32_t)idx << 6) | subs)); }
        CLS(0)  CLS(1)  CLS(2)  CLS(3)  CLS(4)  CLS(5)  CLS(6)  CLS(7)
        CLS(8)  CLS(9)  CLS(10) CLS(11) CLS(12) CLS(13) CLS(14) CLS(15)
#undef CLS

        // ---- latency cover: next-row prefetch + bitmap target flags ----
        int4 pre; uint4 qnext; uint2 pre_bm; int snext;
        if (hasNext) {
            pre    = ((const int4*)(inds + ((size_t)rown << 10)))[tid];
            qnext  = *(const uint4*)(q16 + ((size_t)rown << 6) + subs);
            snext  = seg32[rown];
            pre_bm = ((const uint2*)(sbm + ((size_t)(snext & 63) << 9)))[tid];
        }
        int tfm = 0;
        if ((bm_lds[p][(uint32_t)iv.x >> 5] >> (iv.x & 31)) & 1u) tfm |= 1;
        if ((bm_lds[p][(uint32_t)iv.y >> 5] >> (iv.y & 31)) & 1u) tfm |= 2;
        if ((bm_lds[p][(uint32_t)iv.z >> 5] >> (iv.z & 31)) & 1u) tfm |= 4;
        if ((bm_lds[p][(uint32_t)iv.w >> 5] >> (iv.w & 31)) & 1u) tfm |= 8;
        __builtin_amdgcn_sched_barrier(0);

        // ---- pass 2: LDS-or-register key, dots, quad reduce, owner capture --
        float lg0 = 0.f, lg1 = 0.f, lg2 = 0.f, lg3 = 0.f;
#define DOT(I) { \
        int comp = (((I)&3)==0) ? iv.x : (((I)&3)==1) ? iv.y : (((I)&3)==2) ? iv.z : iv.w; \
        int idx  = qbcast<((I)>>2)>(comp); \
        int rr = (idx >> 7) - yL, cc = (idx & 127) - xL; \
        uint4 kc = kd[(I)]; \
        if ((uint32_t)rr < (uint32_t)wh && (uint32_t)cc < (uint32_t)ww) \
            kc = *(const uint4*)(key_lds + ((((rr << 5) + cc) << 6) | subs)); \
        union { uint4 u; h2 h[4]; } kk; kk.u = kc; \
        float acc = dot2(kk.h[0], qh0, 0.f); \
        acc = dot2(kk.h[1], qh1, acc); \
        acc = dot2(kk.h[2], qh2, acc); \
        acc = dot2(kk.h[3], qh3, acc); \
        acc = dpp_add<0xB1>(acc); \
        acc = dpp_add<0x4E>(acc); \
        if (sub == ((I) >> 2)) { \
            if constexpr (((I)&3) == 0) lg0 = acc; \
            else if constexpr (((I)&3) == 1) lg1 = acc; \
            else if constexpr (((I)&3) == 2) lg2 = acc; \
            else lg3 = acc; } }
        DOT(0)  DOT(1)  DOT(2)  DOT(3)  DOT(4)  DOT(5)  DOT(6)  DOT(7)
        DOT(8)  DOT(9)  DOT(10) DOT(11) DOT(12) DOT(13) DOT(14) DOT(15)
#undef DOT

        // ---- logit store: lane owns samples tid*4..tid*4+3 -> one float4 ----
        *(float4*)(out + ((size_t)row << 10) + (tid << 2)) =
            make_float4(lg0, lg1, lg2, lg3);

        // ---- per-lane partials: Z (no max-sub; |logit|<~8), T, SL ----
        float z  = (__expf(lg0) + __expf(lg1)) + (__expf(lg2) + __expf(lg3));
        float tc = (float)__popc((unsigned)tfm);
        float sl = 0.f;
        sl += (tfm & 1) ? lg0 : 0.f;
        sl += (tfm & 2) ? lg1 : 0.f;
        sl += (tfm & 4) ? lg2 : 0.f;
        sl += (tfm & 8) ? lg3 : 0.f;
#pragma unroll
        for (int off = 32; off >= 1; off >>= 1) {
            z  += __shfl_xor(z,  off, 64);
            tc += __shfl_xor(tc, off, 64);
            sl += __shfl_xor(sl, off, 64);
        }
        if (lane == 0) {
            red[p][0][w] = z;
            red[p][1][w] = tc;
            red[p][2][w] = sl;
        }

        // ---- commit prefetch into the other parity slot ----
        if (hasNext) {
            ((uint2*)bm_lds[p ^ 1])[tid] = pre_bm;
            ivcur = pre;
            qcur  = qnext;
        }
        __syncthreads();                   // THE one barrier per row

        if (tid == 0) {
            if (seg_n != 0) {
                const float Z  = (red[p][0][0] + red[p][0][1]) + (red[p][0][2] + red[p][0][3]);
                const float T  = (red[p][1][0] + red[p][1][1]) + (red[p][1][2] + red[p][1][3]);
                const float SL = (red[p][2][0] + red[p][2][1]) + (red[p][2][2] + red[p][2][3]);
                // closed-form KL; T >= 1 (center sample matches itself)
                ws_kl[row] = -__logf(T) - SL / T + __logf(Z);
            } else {
                ws_kl[row] = 0.f;
            }
        }

        if (hasNext) {
            row  = rown;
            scur = snext;
        }
    }
}

// ---------------------------------------------------------------------------
// Fallback (generic shapes / tiny ws): per-thread gather from native layout.
// ---------------------------------------------------------------------------
__global__ __launch_bounds__(256)
void affinity_fallback(const float* __restrict__ key_f,
                       const float* __restrict__ query_f,
                       const int*   __restrict__ seg32,
                       const int*   __restrict__ inds,
                       float* __restrict__ out,
                       float* __restrict__ ws_kl,
                       int N, int S, float scale)
{
    const int bid = blockIdx.x;
    const int tid = threadIdx.x;
    const int b   = bid / N;

    __shared__ float q_lds[CDIM];
    __shared__ float redA[4], redB[4], redC[4];

    if (tid < CDIM) {
        int n = bid - b * N;
        q_lds[tid] = query_f[((size_t)(b * CDIM + tid)) * N + n];
    }
    const int seg_n = seg32[bid];
    __syncthreads();

    float q[CDIM];
#pragma unroll
    for (int c = 0; c < CDIM; ++c) q[c] = q_lds[c];

    const size_t rowbase = (size_t)bid * S;
    const int4 iv = ((const int4*)(inds + rowbase))[tid];
    const int idxv[4] = {iv.x, iv.y, iv.z, iv.w};

    float lg[4];
    int   tf[4];
#pragma unroll
    for (int k = 0; k < 4; ++k) {
        int idx = idxv[k];
        tf[k] = (seg32[b * N + idx] == seg_n) ? 1 : 0;
        float acc = 0.f;
#pragma unroll
        for (int c = 0; c < CDIM; ++c)
            acc = fmaf(key_f[((size_t)(b * CDIM + c)) * N + idx], q[c], acc);
        lg[k] = acc * scale;
    }
    ((float4*)(out + rowbase))[tid] = make_float4(lg[0], lg[1], lg[2], lg[3]);

    const int lane = tid & 63, wv = tid >> 6;
    float m = fmaxf(fmaxf(lg[0], lg[1]), fmaxf(lg[2], lg[3]));
#pragma unroll
    for (int off = 32; off >= 1; off >>= 1)
        m = fmaxf(m, __shfl_xor(m, off, 64));
    if (lane == 0) redA[wv] = m;
    __syncthreads();
    m = fmaxf(fmaxf(redA[0], redA[1]), fmaxf(redA[2], redA[3]));

    float e[4], z = 0.f, tcnt = 0.f;
#pragma unroll
    for (int k = 0; k < 4; ++k) {
        e[k] = expf(lg[k] - m);
        z += e[k];
        tcnt += (float)tf[k];
    }
#pragma unroll
    for (int off = 32; off >= 1; off >>= 1) {
        z    += __shfl_xor(z, off, 64);
        tcnt += __shfl_xor(tcnt, off, 64);
    }
    if (lane == 0) { redB[wv] = z; redC[wv] = tcnt; }
    __syncthreads();
    const float Z = redB[0] + redB[1] + redB[2] + redB[3];
    const float T = redC[0] + redC[1] + redC[2] + redC[3];

    float kl = 0.f;
    if (seg_n != 0) {
        const float invZ = 1.f / (Z + 1e-9f);
        const float invT = 1.f / (T + 1e-9f);
        const float nlT  = -logf(T + 1e-9f);
#pragma unroll
        for (int k = 0; k < 4; ++k) {
            if (tf[k]) {
                float p = e[k] * invZ;
                float yp = logf(fmaxf(p, 1e-8f));
                kl += invT * (nlT - yp);
            }
        }
    }
#pragma unroll
    for (int off = 32; off >= 1; off >>= 1)
        kl += __shfl_xor(kl, off, 64);
    if (lane == 0) redA[wv] = kl;
    __syncthreads();
    if (tid == 0)
        ws_kl[bid] = redA[0] + redA[1] + redA[2] + redA[3];
}

// ---------------------------------------------------------------------------
// Kernel 3: deterministic single-block loss reduction (1024 threads).
// ---------------------------------------------------------------------------
__global__ __launch_bounds__(1024)
void loss_reduce(const float* __restrict__ ws_kl,
                 const int* __restrict__ seg32,
                 float* __restrict__ out_loss, int rows)
{
    const int tid = threadIdx.x;
    float s = 0.f, c = 0.f;
    for (int i = tid; i < rows; i += 1024) {
        s += ws_kl[i];
        c += (seg32[i] != 0) ? 1.f : 0.f;
    }
#pragma unroll
    for (int off = 32; off >= 1; off >>= 1) {
        s += __shfl_xor(s, off, 64);
        c += __shfl_xor(c, off, 64);
    }
    __shared__ float sA[16], sB[16];
    const int lane = tid & 63, wv = tid >> 6;
    if (lane == 0) { sA[wv] = s; sB[wv] = c; }
    __syncthreads();
    if (tid == 0) {
        float ts = 0.f, tc = 0.f;
#pragma unroll
        for (int k = 0; k < 16; ++k) { ts += sA[k]; tc += sB[k]; }
        out_loss[0] = ts / (tc + 1e-9f);
    }
}

// ---------------------------------------------------------------------------
extern "C" void kernel_launch(void* const* d_in, const int* in_sizes, int n_in,
                              void* d_out, int out_size, void* d_ws, size_t ws_size,
                              hipStream_t stream)
{
    const float* key_f   = (const float*)d_in[0];
    const float* query_f = (const float*)d_in[1];
    const int*   seg32   = (const int*)d_in[2];
    const int*   inds    = (const int*)d_in[3];
    float* out = (float*)d_out;

    const int N    = NPIX;
    const int rows = in_sizes[2];            // B*N
    const int S    = in_sizes[3] / rows;     // 1024
    const float scale = (float)(1.0 / sqrt((double)CDIM));
    const int B    = rows / N;

    // ws layout: key16 rows | q16 rows | segbit (B*64*2KB) | kl array
    const size_t off_q16 = (size_t)rows * 64;
    const size_t off_sb  = off_q16 + (size_t)rows * 64;
    const size_t sb_words = (size_t)B * 64 * 512;
    const size_t off_kl  = (off_sb + sb_words * 4 + 255) & ~(size_t)255;
    const size_t need    = off_kl + (size_t)rows * 4;

    uint8_t* wsb = (uint8_t*)d_ws;
    const bool geom_ok = (S == SSAM) && (rows % N == 0);

    if (ws_size >= need && geom_ok) {
        uint8_t*  key16  = wsb;
        uint8_t*  q16    = wsb + off_q16;
        uint32_t* segbit = (uint32_t*)(wsb + off_sb);
        float*    wskl   = (float*)(wsb + off_kl);

        zero_words<<<(int)((sb_words + 255) / 256), 256, 0, stream>>>(
            segbit, (int)sb_words);
        prep_kernel<<<(rows + 255) / 256, 256, 0, stream>>>(
            key_f, query_f, key16, q16, N, rows, scale);
        segbit_build<<<(rows + 255) / 256, 256, 0, stream>>>(
            seg32, segbit, N, rows);
        affinity_tile<<<B * 256, 256, 0, stream>>>(
            inds, key16, q16, seg32, segbit, out, wskl);
        loss_reduce<<<1, 1024, 0, stream>>>(wskl, seg32, out + (size_t)rows * S, rows);
    } else {
        float* wskl = (float*)d_ws;
        affinity_fallback<<<rows, 256, 0, stream>>>(
            key_f, query_f, seg32, inds, out, wskl, N, S, scale);
        loss_reduce<<<1, 1024, 0, stream>>>(wskl, seg32, out + (size_t)rows * S, rows);
    }
}

// Round 12
// 177.486 us; speedup vs baseline: 1.4421x; 1.4421x over previous
//
#include <hip/hip_runtime.h>
#include <stdint.h>

typedef _Float16 h2 __attribute__((ext_vector_type(2)));
typedef unsigned int u32x4 __attribute__((ext_vector_type(4)));

static constexpr int CDIM = 32;     // channels
static constexpr int NPIX = 16384;  // H*W
static constexpr int SSAM = 1024;   // samples per row
static constexpr int ROWS_PER_BLOCK = 16;

__device__ __forceinline__ uint16_t f2h(float f) {
    union { _Float16 h; uint16_t u; } c;
    c.h = (_Float16)f;
    return c.u;
}

// cross-lane add via DPP quad_perm (VALU-only, no LDS pipe).
template<int CTRL>
__device__ __forceinline__ float dpp_add(float x) {
    int y = __builtin_amdgcn_mov_dpp(__float_as_int(x), CTRL, 0xF, 0xF, true);
    return x + __int_as_float(y);
}

__device__ __forceinline__ float dot2(h2 a, h2 b, float c) {
    return __builtin_amdgcn_fdot2(a, b, c, false);   // v_dot2_f32_f16
}

// ---------------------------------------------------------------------------
// Kernel 1: layout prep (+ zero the segbit region: 2 words per thread).
//   key_feat  [B][C][N] f32 -> key16 [B*N][32] f16 rows (64B, line-aligned)
//   query_feat[B][C][N] f32 -> q16   [B*N][32] f16 rows, PRE-SCALED by C^-0.5
// ---------------------------------------------------------------------------
__global__ __launch_bounds__(256)
void prep_kernel(const float* __restrict__ key_f,
                 const float* __restrict__ query_f,
                 uint8_t* __restrict__ key16,
                 uint8_t* __restrict__ q16,
                 uint32_t* __restrict__ segbit,   // words = 2*rows, zeroed here
                 int N, int rows, float scale)
{
    int gI = blockIdx.x * 256 + threadIdx.x;
    if (gI >= rows) return;
    segbit[2 * gI]     = 0;
    segbit[2 * gI + 1] = 0;

    int b = gI / N, n = gI - b * N;
    const size_t cb = (size_t)b * CDIM;

    uint32_t kp[16], qp[16];
#pragma unroll
    for (int c = 0; c < CDIM; c += 2) {
        float k0 = key_f[(cb + c) * N + n];
        float k1 = key_f[(cb + c + 1) * N + n];
        float q0 = query_f[(cb + c) * N + n] * scale;
        float q1 = query_f[(cb + c + 1) * N + n] * scale;
        kp[c >> 1] = (uint32_t)f2h(k0) | ((uint32_t)f2h(k1) << 16);
        qp[c >> 1] = (uint32_t)f2h(q0) | ((uint32_t)f2h(q1) << 16);
    }
    uint4* ko = (uint4*)(key16 + ((size_t)gI << 6));
    uint4* qo = (uint4*)(q16 + ((size_t)gI << 6));
#pragma unroll
    for (int j = 0; j < 4; ++j) {
        ko[j] = make_uint4(kp[4*j], kp[4*j+1], kp[4*j+2], kp[4*j+3]);
        qo[j] = make_uint4(qp[4*j], qp[4*j+1], qp[4*j+2], qp[4*j+3]);
    }
}

// ---------------------------------------------------------------------------
// Kernel 1b: segment bitmap. segbit[b][v][512]: bit n set iff seg[b][n]==v.
// ---------------------------------------------------------------------------
__global__ __launch_bounds__(256)
void segbit_build(const int* __restrict__ seg32,
                  uint32_t* __restrict__ segbit,
                  int N, int rows)
{
    int g = blockIdx.x * 256 + threadIdx.x;
    if (g >= rows) return;
    int b = g / N, n = g - b * N;
    int v = seg32[g] & 63;
    atomicOr(&segbit[(((size_t)(b * 64 + v)) << 9) + (n >> 5)], 1u << (n & 31));
}

// ---------------------------------------------------------------------------
// Kernel 2 (fast): R9 base (persistent 16-row blocks, 1 barrier/row, segbit,
// closed-form KL, no row-max) + the TRUE depth-16 gather experiment:
//  - ONE asm block with all 16 global_load_dwordx4 sc0 (agent scope = L1
//    bypass; keys are L2-resident, L1 is a pure miss-alloc tax). Single
//    unsplittable unit + "memory" clobber -> nothing interleaves, 16 loads
//    in flight per wave guaranteed (R7's separate-asm attempt failed: dots
//    were interleaved, VGPR=56 < 64 proved it).
//  - Counted drain: prefetch (3 vmem loads, fenced between block and drain
//    by the memory clobbers) stays in flight across the drain via vmcnt(3).
//  - sched_barrier(0) after drain (rule #18).
// Fixed geometry: N=16384, S=1024, C=32, 16 rows/block.
// ---------------------------------------------------------------------------
__global__ __launch_bounds__(256)
void affinity_multi(const int* __restrict__ inds,
                    const uint8_t* __restrict__ key16,
                    const uint8_t* __restrict__ q16,
                    const int* __restrict__ seg32,
                    const uint32_t* __restrict__ segbit,
                    float* __restrict__ out,
                    float* __restrict__ ws_kl)
{
    const int tid  = threadIdx.x;
    const int row0 = blockIdx.x * ROWS_PER_BLOCK;
    const int b    = row0 >> 14;           // N = 16384; 16 | N so batch uniform
    const int lane = tid & 63;
    const int w    = tid >> 6;             // wave 0..3
    const int g    = lane >> 2;            // group 0..15
    const int sub  = lane & 3;             // quarter 0..3

    __shared__ __align__(16) int      idx_lds[2][SSAM];  // 2 x 4KB (per-wave)
    __shared__ __align__(16) uint32_t bm_lds[2][512];    // 2 x 2KB bitmap
    __shared__ float red[2][3][4];                       // [parity][Z,T,SL][wave]

    const uint32_t* sbase_bm = segbit + ((size_t)(b * 64) << 9);

    // ---- prologue: stage idx/bitmap/query/seg for row0 ----
    ((int4*)idx_lds[0])[tid] = ((const int4*)(inds + ((size_t)row0 << 10)))[tid];
    int scur = seg32[row0];
    ((uint2*)bm_lds[0])[tid] =
        ((const uint2*)(sbase_bm + ((size_t)(scur & 63) << 9)))[tid];
    uint4 qcur = *(const uint4*)(q16 + ((size_t)row0 << 6) + (sub << 4));
    __syncthreads();   // bm_lds visibility

    const uint8_t* kb = key16 + ((size_t)b << 20);      // b * N * 64 (uniform)
    const uint32_t subs = (uint32_t)(sub << 4);
    const int sbase = (w << 8) + g;                     // sample = sbase + i*16

    for (int r = 0; r < ROWS_PER_BLOCK; ++r) {
        const int row = row0 + r;
        const int p   = r & 1;
        const int* cur = idx_lds[p];
        const bool hasNext = (r + 1 < ROWS_PER_BLOCK);

        // unpack this row's query fragment (loaded last iteration)
        h2 qh0, qh1, qh2, qh3;
        {
            union { uint4 u; h2 h[4]; } qc; qc.u = qcur;
            qh0 = qc.h[0]; qh1 = qc.h[1]; qh2 = qc.h[2]; qh3 = qc.h[3];
        }
        const int seg_n = scur;

        // ---- phase 1: 16 indices -> byte offsets ----
        uint32_t voff[16];
#pragma unroll
        for (int i = 0; i < 16; ++i)
            voff[i] = ((uint32_t)cur[sbase + (i << 4)] << 6) | subs;

        // ---- phase 2: ONE asm block, 16 gathers, sc0 (L1 bypass) ----
        u32x4 k0,k1,k2,k3,k4,k5,k6,k7,k8,k9,k10,k11,k12,k13,k14,k15;
        asm volatile(
            "global_load_dwordx4 %0, %16, %32 sc0\n\t"
            "global_load_dwordx4 %1, %17, %32 sc0\n\t"
            "global_load_dwordx4 %2, %18, %32 sc0\n\t"
            "global_load_dwordx4 %3, %19, %32 sc0\n\t"
            "global_load_dwordx4 %4, %20, %32 sc0\n\t"
            "global_load_dwordx4 %5, %21, %32 sc0\n\t"
            "global_load_dwordx4 %6, %22, %32 sc0\n\t"
            "global_load_dwordx4 %7, %23, %32 sc0\n\t"
            "global_load_dwordx4 %8, %24, %32 sc0\n\t"
            "global_load_dwordx4 %9, %25, %32 sc0\n\t"
            "global_load_dwordx4 %10, %26, %32 sc0\n\t"
            "global_load_dwordx4 %11, %27, %32 sc0\n\t"
            "global_load_dwordx4 %12, %28, %32 sc0\n\t"
            "global_load_dwordx4 %13, %29, %32 sc0\n\t"
            "global_load_dwordx4 %14, %30, %32 sc0\n\t"
            "global_load_dwordx4 %15, %31, %32 sc0"
            : "=&v"(k0), "=&v"(k1), "=&v"(k2),  "=&v"(k3),
              "=&v"(k4), "=&v"(k5), "=&v"(k6),  "=&v"(k7),
              "=&v"(k8), "=&v"(k9), "=&v"(k10), "=&v"(k11),
              "=&v"(k12),"=&v"(k13),"=&v"(k14), "=&v"(k15)
            : "v"(voff[0]),  "v"(voff[1]),  "v"(voff[2]),  "v"(voff[3]),
              "v"(voff[4]),  "v"(voff[5]),  "v"(voff[6]),  "v"(voff[7]),
              "v"(voff[8]),  "v"(voff[9]),  "v"(voff[10]), "v"(voff[11]),
              "v"(voff[12]), "v"(voff[13]), "v"(voff[14]), "v"(voff[15]),
              "s"(kb)
            : "memory");

        // ---- latency cover (fenced between block and drain by the memory
        //      clobbers): exactly 3 vmem prefetch loads + LDS tfm ----
        int4 pre; uint4 qnext; uint2 pre_bm; int snext;
        if (hasNext) {
            pre    = ((const int4*)(inds + ((size_t)(row + 1) << 10)))[tid];
            qnext  = *(const uint4*)(q16 + ((size_t)(row + 1) << 6) + (sub << 4));
            snext  = seg32[row + 1];
            pre_bm = ((const uint2*)(sbase_bm + ((size_t)(snext & 63) << 9)))[tid];
        }
        int tfm = 0;
#pragma unroll
        for (int j = 0; j < 4; ++j) {
            int idx = cur[sbase + (((j << 2) | sub) << 4)];
            if ((bm_lds[p][idx >> 5] >> (idx & 31)) & 1u) tfm |= 1 << j;
        }

        // ---- counted drain: gathers done, prefetch stays in flight ----
        __builtin_amdgcn_sched_barrier(0);
        if (hasNext) asm volatile("s_waitcnt vmcnt(3)" ::: "memory");
        else         asm volatile("s_waitcnt vmcnt(0)" ::: "memory");
        __builtin_amdgcn_sched_barrier(0);   // rule #18: pin dots below drain

        // ---- phase 3: dots + quad reduce + owner capture ----
        float lg0 = 0.f, lg1 = 0.f, lg2 = 0.f, lg3 = 0.f;
#define DOT(I, KV) { \
        union { u32x4 u; h2 h[4]; } kk; kk.u = (KV); \
        float acc = dot2(kk.h[0], qh0, 0.f); \
        acc = dot2(kk.h[1], qh1, acc); \
        acc = dot2(kk.h[2], qh2, acc); \
        acc = dot2(kk.h[3], qh3, acc); \
        acc = dpp_add<0xB1>(acc); \
        acc = dpp_add<0x4E>(acc); \
        if (sub == ((I) & 3)) { \
            if constexpr (((I) >> 2) == 0) lg0 = acc; \
            else if constexpr (((I) >> 2) == 1) lg1 = acc; \
            else if constexpr (((I) >> 2) == 2) lg2 = acc; \
            else lg3 = acc; } }
        DOT(0,k0)   DOT(1,k1)   DOT(2,k2)   DOT(3,k3)
        DOT(4,k4)   DOT(5,k5)   DOT(6,k6)   DOT(7,k7)
        DOT(8,k8)   DOT(9,k9)   DOT(10,k10) DOT(11,k11)
        DOT(12,k12) DOT(13,k13) DOT(14,k14) DOT(15,k15)
#undef DOT

        // ---- owner-lane full-wave logit stores (4 insts, coalesced) ----
        const size_t rowbase = (size_t)row << 10;
        float* op = out + rowbase + (w << 8) + (sub << 4) + g;
        op[0]   = lg0;
        op[64]  = lg1;
        op[128] = lg2;
        op[192] = lg3;

        // ---- per-lane partials: Z (no max-sub; |logit|<~8), T, SL ----
        float z  = (__expf(lg0) + __expf(lg1)) + (__expf(lg2) + __expf(lg3));
        float tc = (float)__popc((unsigned)tfm);
        float sl = 0.f;
        sl += (tfm & 1) ? lg0 : 0.f;
        sl += (tfm & 2) ? lg1 : 0.f;
        sl += (tfm & 4) ? lg2 : 0.f;
        sl += (tfm & 8) ? lg3 : 0.f;
#pragma unroll
        for (int off = 32; off >= 1; off >>= 1) {
            z  += __shfl_xor(z,  off, 64);
            tc += __shfl_xor(tc, off, 64);
            sl += __shfl_xor(sl, off, 64);
        }
        if (lane == 0) {
            red[p][0][w] = z;
            red[p][1][w] = tc;
            red[p][2][w] = sl;
        }

        // ---- commit prefetch into the other parity slots ----
        if (hasNext) {
            ((int4*)idx_lds[p ^ 1])[tid] = pre;
            ((uint2*)bm_lds[p ^ 1])[tid] = pre_bm;
            qcur = qnext;
            scur = snext;
        }
        __syncthreads();                   // THE one barrier per row

        if (tid == 0) {
            if (seg_n != 0) {
                const float Z  = (red[p][0][0] + red[p][0][1]) + (red[p][0][2] + red[p][0][3]);
                const float T  = (red[p][1][0] + red[p][1][1]) + (red[p][1][2] + red[p][1][3]);
                const float SL = (red[p][2][0] + red[p][2][1]) + (red[p][2][2] + red[p][2][3]);
                // closed-form KL; T >= 1 (center sample matches itself)
                ws_kl[row] = -__logf(T) - SL / T + __logf(Z);
            } else {
                ws_kl[row] = 0.f;
            }
        }
    }
}

// ---------------------------------------------------------------------------
// Fallback (generic shapes / tiny ws): per-thread gather from native layout.
// ---------------------------------------------------------------------------
__global__ __launch_bounds__(256)
void affinity_fallback(const float* __restrict__ key_f,
                       const float* __restrict__ query_f,
                       const int*   __restrict__ seg32,
                       const int*   __restrict__ inds,
                       float* __restrict__ out,
                       float* __restrict__ ws_kl,
                       int N, int S, float scale)
{
    const int bid = blockIdx.x;
    const int tid = threadIdx.x;
    const int b   = bid / N;

    __shared__ float q_lds[CDIM];
    __shared__ float redA[4], redB[4], redC[4];

    if (tid < CDIM) {
        int n = bid - b * N;
        q_lds[tid] = query_f[((size_t)(b * CDIM + tid)) * N + n];
    }
    const int seg_n = seg32[bid];
    __syncthreads();

    float q[CDIM];
#pragma unroll
    for (int c = 0; c < CDIM; ++c) q[c] = q_lds[c];

    const size_t rowbase = (size_t)bid * S;
    const int4 iv = ((const int4*)(inds + rowbase))[tid];
    const int idxv[4] = {iv.x, iv.y, iv.z, iv.w};

    float lg[4];
    int   tf[4];
#pragma unroll
    for (int k = 0; k < 4; ++k) {
        int idx = idxv[k];
        tf[k] = (seg32[b * N + idx] == seg_n) ? 1 : 0;
        float acc = 0.f;
#pragma unroll
        for (int c = 0; c < CDIM; ++c)
            acc = fmaf(key_f[((size_t)(b * CDIM + c)) * N + idx], q[c], acc);
        lg[k] = acc * scale;
    }
    ((float4*)(out + rowbase))[tid] = make_float4(lg[0], lg[1], lg[2], lg[3]);

    const int lane = tid & 63, wv = tid >> 6;
    float m = fmaxf(fmaxf(lg[0], lg[1]), fmaxf(lg[2], lg[3]));
#pragma unroll
    for (int off = 32; off >= 1; off >>= 1)
        m = fmaxf(m, __shfl_xor(m, off, 64));
    if (lane == 0) redA[wv] = m;
    __syncthreads();
    m = fmaxf(fmaxf(redA[0], redA[1]), fmaxf(redA[2], redA[3]));

    float e[4], z = 0.f, tcnt = 0.f;
#pragma unroll
    for (int k = 0; k < 4; ++k) {
        e[k] = expf(lg[k] - m);
        z += e[k];
        tcnt += (float)tf[k];
    }
#pragma unroll
    for (int off = 32; off >= 1; off >>= 1) {
        z    += __shfl_xor(z, off, 64);
        tcnt += __shfl_xor(tcnt, off, 64);
    }
    if (lane == 0) { redB[wv] = z; redC[wv] = tcnt; }
    __syncthreads();
    const float Z = redB[0] + redB[1] + redB[2] + redB[3];
    const float T = redC[0] + redC[1] + redC[2] + redC[3];

    float kl = 0.f;
    if (seg_n != 0) {
        const float invZ = 1.f / (Z + 1e-9f);
        const float invT = 1.f / (T + 1e-9f);
        const float nlT  = -logf(T + 1e-9f);
#pragma unroll
        for (int k = 0; k < 4; ++k) {
            if (tf[k]) {
                float p = e[k] * invZ;
                float yp = logf(fmaxf(p, 1e-8f));
                kl += invT * (nlT - yp);
            }
        }
    }
#pragma unroll
    for (int off = 32; off >= 1; off >>= 1)
        kl += __shfl_xor(kl, off, 64);
    if (lane == 0) redA[wv] = kl;
    __syncthreads();
    if (tid == 0)
        ws_kl[bid] = redA[0] + redA[1] + redA[2] + redA[3];
}

// ---------------------------------------------------------------------------
// Kernel 3: deterministic single-block loss reduction (1024 threads).
// ---------------------------------------------------------------------------
__global__ __launch_bounds__(1024)
void loss_reduce(const float* __restrict__ ws_kl,
                 const int* __restrict__ seg32,
                 float* __restrict__ out_loss, int rows)
{
    const int tid = threadIdx.x;
    float s = 0.f, c = 0.f;
    for (int i = tid; i < rows; i += 1024) {
        s += ws_kl[i];
        c += (seg32[i] != 0) ? 1.f : 0.f;
    }
#pragma unroll
    for (int off = 32; off >= 1; off >>= 1) {
        s += __shfl_xor(s, off, 64);
        c += __shfl_xor(c, off, 64);
    }
    __shared__ float sA[16], sB[16];
    const int lane = tid & 63, wv = tid >> 6;
    if (lane == 0) { sA[wv] = s; sB[wv] = c; }
    __syncthreads();
    if (tid == 0) {
        float ts = 0.f, tc = 0.f;
#pragma unroll
        for (int k = 0; k < 16; ++k) { ts += sA[k]; tc += sB[k]; }
        out_loss[0] = ts / (tc + 1e-9f);
    }
}

// ---------------------------------------------------------------------------
extern "C" void kernel_launch(void* const* d_in, const int* in_sizes, int n_in,
                              void* d_out, int out_size, void* d_ws, size_t ws_size,
                              hipStream_t stream)
{
    const float* key_f   = (const float*)d_in[0];
    const float* query_f = (const float*)d_in[1];
    const int*   seg32   = (const int*)d_in[2];
    const int*   inds    = (const int*)d_in[3];
    float* out = (float*)d_out;

    const int N    = NPIX;
    const int rows = in_sizes[2];            // B*N
    const int S    = in_sizes[3] / rows;     // 1024
    const float scale = (float)(1.0 / sqrt((double)CDIM));
    const int B    = rows / N;

    // ws layout: key16 rows | q16 rows | segbit (B*64*2KB = 2*rows words) | kl
    const size_t off_q16 = (size_t)rows * 64;
    const size_t off_sb  = off_q16 + (size_t)rows * 64;
    const size_t sb_words = (size_t)B * 64 * 512;   // == 2*rows
    const size_t off_kl  = (off_sb + sb_words * 4 + 255) & ~(size_t)255;
    const size_t need    = off_kl + (size_t)rows * 4;

    uint8_t* wsb = (uint8_t*)d_ws;
    const bool geom_ok = (S == SSAM) && (rows % N == 0) &&
                         (rows % ROWS_PER_BLOCK == 0);

    if (ws_size >= need && geom_ok) {
        uint8_t*  key16  = wsb;
        uint8_t*  q16    = wsb + off_q16;
        uint32_t* segbit = (uint32_t*)(wsb + off_sb);
        float*    wskl   = (float*)(wsb + off_kl);

        prep_kernel<<<(rows + 255) / 256, 256, 0, stream>>>(
            key_f, query_f, key16, q16, segbit, N, rows, scale);
        segbit_build<<<(rows + 255) / 256, 256, 0, stream>>>(
            seg32, segbit, N, rows);
        affinity_multi<<<rows / ROWS_PER_BLOCK, 256, 0, stream>>>(
            inds, key16, q16, seg32, segbit, out, wskl);
        loss_reduce<<<1, 1024, 0, stream>>>(wskl, seg32, out + (size_t)rows * S, rows);
    } else {
        float* wskl = (float*)d_ws;
        affinity_fallback<<<rows, 256, 0, stream>>>(
            key_f, query_f, seg32, inds, out, wskl, N, S, scale);
        loss_reduce<<<1, 1024, 0, stream>>>(wskl, seg32, out + (size_t)rows * S, rows);
    }
}